// Round 1
// baseline (2289.159 us; speedup 1.0000x reference)
//
#include <hip/hip_runtime.h>
#include <hip/hip_bf16.h>

#define TSTEPS 512

typedef _Float16 h2t __attribute__((ext_vector_type(2)));
typedef _Float16 h8t __attribute__((ext_vector_type(8)));

__device__ __forceinline__ float fdot2(h2t a, h2t b, float c){
#if __has_builtin(__builtin_amdgcn_fdot2)
    return __builtin_amdgcn_fdot2(a, b, c, false);
#else
    return c + (float)a[0]*(float)b[0] + (float)a[1]*(float)b[1];
#endif
}

__device__ __forceinline__ float rcp_(float x){
#if __has_builtin(__builtin_amdgcn_rcpf)
    return __builtin_amdgcn_rcpf(x);
#else
    return 1.0f/x;
#endif
}

__device__ __forceinline__ float sigf(float x){
    return rcp_(1.0f + __expf(-x));
}
__device__ __forceinline__ float tanhf_(float x){
    float e = __expf(-2.0f*fabsf(x));
    float r = (1.0f - e) * rcp_(1.0f + e);
    return copysignf(r, x);
}
__device__ __forceinline__ float pick(int d, float x0, float x1, float x2, float x3){
    return d==0 ? x0 : (d==1 ? x1 : (d==2 ? x2 : x3));
}
__device__ __forceinline__ h2t pkh(float a, float b){
    h2t r; r[0] = (_Float16)a; r[1] = (_Float16)b; return r;
}

// z -> activated gates gathered across the 4-lane quad -> c update -> h
__device__ __forceinline__ float gate_update(float z, float& c, int gq){
    float a  = (gq == 2) ? tanhf_(z) : sigf(z);
    float a1 = __shfl_xor(a, 1);
    float a2 = __shfl_xor(a, 2);
    float a3 = __shfl_xor(a1, 2);
    float i_ = pick(gq,   a, a1, a2, a3);   // row 0 (i)
    float f_ = pick(gq^1, a, a1, a2, a3);   // row 1 (f)
    float gg = pick(gq^2, a, a1, a2, a3);   // row 2 (g)
    float o_ = pick(gq^3, a, a1, a2, a3);   // row 3 (o)
    c = fmaf(f_, c, i_*gg);
    return o_ * tanhf_(c);
}

// 64-length f16 dot for both batch elements; BASE points at [2][64] f16 block
#define DOT64(BASE, W, ZA, ZB) do { \
    const _Float16* _bp = (BASE); \
    _Pragma("unroll") \
    for (int _c = 0; _c < 8; ++_c){ \
        h8t _va = *(const h8t*)(_bp + _c*8); \
        h8t _vb = *(const h8t*)(_bp + 64 + _c*8); \
        _Pragma("unroll") \
        for (int _j = 0; _j < 4; ++_j){ \
            h2t _ha = {_va[2*_j], _va[2*_j+1]}; \
            h2t _hb = {_vb[2*_j], _vb[2*_j+1]}; \
            ZA = fdot2(W[_c*4+_j], _ha, ZA); \
            ZB = fdot2(W[_c*4+_j], _hb, ZB); \
        } \
    } \
} while(0)

#define LOADW(W, SRC) do { \
    const float* _p = (SRC); \
    _Pragma("unroll") \
    for (int _k = 0; _k < 32; ++_k) W[_k] = pkh(_p[2*_k], _p[2*_k+1]); \
} while(0)

__global__ __launch_bounds__(256, 2) void lstm3_kernel(
    const float* __restrict__ x,
    const float* __restrict__ w_ih1, const float* __restrict__ w_hh1, const float* __restrict__ b1,
    const float* __restrict__ w_ih2, const float* __restrict__ w_hh2, const float* __restrict__ b2,
    const float* __restrict__ w_ih3, const float* __restrict__ w_hh3, const float* __restrict__ b3,
    const float* __restrict__ fc1_w, const float* __restrict__ fc1_b,
    const float* __restrict__ fc2_w, const float* __restrict__ fc2_b,
    float* __restrict__ out)
{
    // h buffers: [layer][pingpong][batch][64] f16, double-buffered per step
    __shared__ __align__(16) _Float16 hall[3][2][2][64];
    __shared__ __align__(16) float    x_lds[2*TSTEPS];
    __shared__ __align__(16) _Float16 fc1_lds[32*72];   // stride 72 to rotate banks

    const int tid = threadIdx.x;
    const int e   = tid >> 2;       // element 0..63
    const int g   = tid & 3;        // gate   0..3 (i,f,g,o)
    const int r   = g*64 + e;       // original weight row
    const int b0g = blockIdx.x * 2; // two batch elements per block

    // stage x: x_lds[t*2 + b]
    for (int i = tid; i < 2*TSTEPS; i += 256){
        int tt = i >> 1, bb = i & 1;
        x_lds[i] = x[(size_t)(b0g + bb)*TSTEPS + tt];
    }
    // stage fc1_w as f16
    for (int i = tid; i < 32*64; i += 256){
        int mm = i >> 6, k = i & 63;
        fc1_lds[mm*72 + k] = (_Float16)fc1_w[i];
    }
    // zero h buffers
    {
        _Float16* hz = &hall[0][0][0][0];
        for (int i = tid; i < 3*2*2*64; i += 256) hz[i] = (_Float16)0.0f;
    }

    // persistent per-thread weights (packed f16)
    h2t whh1v[32], wih2v[32], whh2v[32], wih3v[32], whh3v[32];
    LOADW(whh1v, w_hh1 + r*64);
    LOADW(wih2v, w_ih2 + r*64);
    LOADW(whh2v, w_hh2 + r*64);
    LOADW(wih3v, w_ih3 + r*64);
    LOADW(whh3v, w_hh3 + r*64);

    const float wih1r = w_ih1[r];
    const float b1r = b1[r], b2r = b2[r], b3r = b3[r];

    const int   m     = tid & 31;
    const float fc1br = fc1_b[m];
    const float fc2wr = fc2_w[m];
    const float fc2br = fc2_b[0];

    float c1a = 0.f, c1b = 0.f, c2a = 0.f, c2b = 0.f, c3a = 0.f, c3b = 0.f;

    __syncthreads();

    for (int t = 0; t < TSTEPS; ++t){
        const int pp = t & 1, qq = pp ^ 1;

        // ---------------- Layer 1: z = x*w_ih1 + h1 . w_hh1 + b1 ----------------
        float2 xv = *(const float2*)&x_lds[2*t];
        float za = fmaf(xv.x, wih1r, b1r);
        float zb = fmaf(xv.y, wih1r, b1r);
        DOT64(&hall[0][pp][0][0], whh1v, za, zb);

        float h1a = gate_update(za, c1a, g);
        float h1b = gate_update(zb, c1b, g);
        if (g == 0){
            hall[0][qq][0][e] = (_Float16)h1a;
            hall[0][qq][1][e] = (_Float16)h1b;
        }
        __syncthreads();

        // ---------------- Layer 2: z = h1' . w_ih2 + h2 . w_hh2 + b2 ----------------
        za = b2r; zb = b2r;
        DOT64(&hall[0][qq][0][0], wih2v, za, zb);
        DOT64(&hall[1][pp][0][0], whh2v, za, zb);

        float h2a = gate_update(za, c2a, g);
        float h2b = gate_update(zb, c2b, g);
        if (g == 0){
            hall[1][qq][0][e] = (_Float16)h2a;
            hall[1][qq][1][e] = (_Float16)h2b;
        }
        __syncthreads();

        // ---------------- Layer 3 ----------------
        za = b3r; zb = b3r;
        DOT64(&hall[1][qq][0][0], wih3v, za, zb);
        DOT64(&hall[2][pp][0][0], whh3v, za, zb);

        float h3a = gate_update(za, c3a, g);
        float h3b = gate_update(zb, c3b, g);
        if (g == 0){
            hall[2][qq][0][e] = (_Float16)h3a;
            hall[2][qq][1][e] = (_Float16)h3b;
        }
        __syncthreads();

        // ---------------- FC head (wave 0 only) ----------------
        if (tid < 64){
            const int bb = tid >> 5;
            float y = fc1br;
            const _Float16* hp = &hall[2][qq][bb][0];
            const _Float16* wp = &fc1_lds[m*72];
            #pragma unroll
            for (int c8 = 0; c8 < 8; ++c8){
                h8t hv = *(const h8t*)(hp + c8*8);
                h8t wv = *(const h8t*)(wp + c8*8);
                #pragma unroll
                for (int j2 = 0; j2 < 4; ++j2){
                    h2t wa = {wv[2*j2], wv[2*j2+1]};
                    h2t ha = {hv[2*j2], hv[2*j2+1]};
                    y = fdot2(wa, ha, y);
                }
            }
            y = fmaxf(y, 0.2f*y);           // leaky_relu(0.2)
            float s = y * fc2wr;
            s += __shfl_xor(s, 1);
            s += __shfl_xor(s, 2);
            s += __shfl_xor(s, 4);
            s += __shfl_xor(s, 8);
            s += __shfl_xor(s, 16);
            if (m == 0) out[(size_t)(b0g + bb)*TSTEPS + t] = s + fc2br;
        }
    }
}

extern "C" void kernel_launch(void* const* d_in, const int* in_sizes, int n_in,
                              void* d_out, int out_size, void* d_ws, size_t ws_size,
                              hipStream_t stream)
{
    (void)in_sizes; (void)n_in; (void)d_ws; (void)ws_size; (void)out_size;
    const float* x     = (const float*)d_in[0];
    const float* w_ih1 = (const float*)d_in[1];
    const float* w_hh1 = (const float*)d_in[2];
    const float* b1    = (const float*)d_in[3];
    const float* w_ih2 = (const float*)d_in[4];
    const float* w_hh2 = (const float*)d_in[5];
    const float* b2    = (const float*)d_in[6];
    const float* w_ih3 = (const float*)d_in[7];
    const float* w_hh3 = (const float*)d_in[8];
    const float* b3    = (const float*)d_in[9];
    const float* fc1_w = (const float*)d_in[10];
    const float* fc1_b = (const float*)d_in[11];
    const float* fc2_w = (const float*)d_in[12];
    const float* fc2_b = (const float*)d_in[13];

    lstm3_kernel<<<dim3(512), dim3(256), 0, stream>>>(
        x, w_ih1, w_hh1, b1, w_ih2, w_hh2, b2, w_ih3, w_hh3, b3,
        fc1_w, fc1_b, fc2_w, fc2_b, (float*)d_out);
}

// Round 2
// 873.459 us; speedup vs baseline: 2.6208x; 2.6208x over previous
//
#include <hip/hip_runtime.h>

#define TT 512

typedef _Float16 f16;
typedef _Float16 f16x4 __attribute__((ext_vector_type(4)));
typedef _Float16 f16x8 __attribute__((ext_vector_type(8)));
typedef float    f32x4 __attribute__((ext_vector_type(4)));

#define MFMA(A, B, C) __builtin_amdgcn_mfma_f32_16x16x32_f16((A), (B), (C), 0, 0, 0)

__device__ __forceinline__ float exp2f_(float x){
#if __has_builtin(__builtin_amdgcn_exp2f)
    return __builtin_amdgcn_exp2f(x);
#else
    return exp2f(x);
#endif
}
__device__ __forceinline__ float rcp_(float x){
#if __has_builtin(__builtin_amdgcn_rcpf)
    return __builtin_amdgcn_rcpf(x);
#else
    return 1.0f/x;
#endif
}
__device__ __forceinline__ float sigf(float x){
    return rcp_(1.0f + exp2f_(-1.44269504f*x));
}
__device__ __forceinline__ float tanhf_(float x){
    float e = exp2f_(-2.88539008f*fabsf(x));
    float r = (1.0f - e)*rcp_(1.0f + e);
    return copysignf(r, x);
}
__device__ __forceinline__ f16x8 ldw8(const float* p){
    f16x8 r;
    #pragma unroll
    for (int i = 0; i < 8; ++i) r[i] = (f16)p[i];
    return r;
}

// 64 blocks x 256 threads (4 waves). Block handles 16 batch elements.
// Wave w owns hidden units [16w,16w+16) of every layer, all 4 gates.
// D = mfma(A=W_tile[16 units][64 k], B=h^T frag) -> D[unit, batch]:
//   lane: batch = lane&15, units = 16w + 4*(lane>>4) + j  (j = acc reg)
// => i,f,g,o for a (batch,unit) pair are all in-lane: no cross-lane gate ops.
__global__ __launch_bounds__(256, 1) void lstm3_mfma(
    const float* __restrict__ x,
    const float* __restrict__ w_ih1, const float* __restrict__ w_hh1, const float* __restrict__ b1,
    const float* __restrict__ w_ih2, const float* __restrict__ w_hh2, const float* __restrict__ b2,
    const float* __restrict__ w_ih3, const float* __restrict__ w_hh3, const float* __restrict__ b3,
    const float* __restrict__ fc1_w, const float* __restrict__ fc1_b,
    const float* __restrict__ fc2_w, const float* __restrict__ fc2_b,
    float* __restrict__ out)
{
    // h buffers: [layer][parity][16 batch][64 units] f16, XOR-swizzled rows.
    __shared__ __align__(16) unsigned char hraw[6*2048];
    __shared__ float x_lds[TT*17];     // [t][batch], +1 pad (17) vs bank stride

    const int tid = threadIdx.x;
    const int w   = tid >> 6;          // wave 0..3
    const int l   = tid & 63;
    const int q   = l >> 4;            // 0..3
    const int bb  = l & 15;            // batch (D-col) AND A-frag row
    const int b0  = blockIdx.x * 16;

    // stage x transposed: coalesced global read, conflict-free LDS write
    for (int i = tid; i < 16*TT; i += 256){
        int b = i >> 9, t = i & (TT-1);
        x_lds[t*17 + b] = x[(size_t)(b0+b)*TT + t];
    }
    for (int i = tid; i < (int)sizeof(hraw)/4; i += 256)
        ((unsigned int*)hraw)[i] = 0u;

    // persistent weight A-fragments: lane = row bb of its 16-row tile,
    // k = 32*kh + 8*q .. +7
    f16x8 wf1[4][2], w2i[4][2], w2h[4][2], w3i[4][2], w3h[4][2];
    #pragma unroll
    for (int g = 0; g < 4; ++g){
        const int row = g*64 + 16*w + bb;
        #pragma unroll
        for (int kh = 0; kh < 2; ++kh){
            const int k0 = kh*32 + q*8;
            wf1[g][kh] = ldw8(w_hh1 + row*64 + k0);
            w2i[g][kh] = ldw8(w_ih2 + row*64 + k0);
            w2h[g][kh] = ldw8(w_hh2 + row*64 + k0);
            w3i[g][kh] = ldw8(w_ih3 + row*64 + k0);
            w3h[g][kh] = ldw8(w_hh3 + row*64 + k0);
        }
    }

    // per-lane scalar constants in D layout (row = g*64 + 16w + 4q + j)
    float wih1r[16], b1r[16], b2r[16], b3r[16];
    #pragma unroll
    for (int g = 0; g < 4; ++g)
    #pragma unroll
    for (int j = 0; j < 4; ++j){
        const int row = g*64 + 16*w + 4*q + j;
        wih1r[g*4+j] = w_ih1[row];
        b1r[g*4+j]   = b1[row];
        b2r[g*4+j]   = b2[row];
        b3r[g*4+j]   = b3[row];
    }

    // FC head fragments (used by wave 0 only; loaded everywhere, regs are free)
    f16x8 wfc[2][2];
    float fc1br[8], fc2wr[8];
    const float fc2bs = fc2_b[0];
    #pragma unroll
    for (int ti = 0; ti < 2; ++ti){
        #pragma unroll
        for (int kh = 0; kh < 2; ++kh)
            wfc[ti][kh] = ldw8(fc1_w + (ti*16 + bb)*64 + kh*32 + q*8);
        #pragma unroll
        for (int j = 0; j < 4; ++j){
            const int col = ti*16 + 4*q + j;
            fc1br[ti*4+j] = fc1_b[col];
            fc2wr[ti*4+j] = fc2_w[col];
        }
    }

    float c1[4] = {0,0,0,0}, c2[4] = {0,0,0,0}, c3[4] = {0,0,0,0};

    // t-invariant LDS byte offsets (XOR swizzle spreads the 16 batch rows)
    const int rowb = bb*128;
    const int swz  = 16*(bb&7);
    const int rd0  = (16*q      ) ^ swz;   // B-frag kh=0: units 8q..8q+7
    const int rd1  = (16*q + 64 ) ^ swz;   // B-frag kh=1
    const int wro  = (32*w + 8*q) ^ swz;   // h write: units 16w+4q..+3 (8B)

    __syncthreads();

    #pragma unroll 1
    for (int t = 0; t < TT; ++t){
        const int pp = t & 1, np = pp ^ 1;
        const unsigned char* h1r = hraw + (0 + pp)*2048;
        unsigned char*       h1w = hraw + (0 + np)*2048;
        const unsigned char* h2r = hraw + (2 + pp)*2048;
        unsigned char*       h2w = hraw + (2 + np)*2048;
        const unsigned char* h3r = hraw + (4 + pp)*2048;
        unsigned char*       h3w = hraw + (4 + np)*2048;

        f32x4 a0, a1, a2, a3;
        f16x4 hn;

        // ---------------- Layer 1: z = b1 + w_ih1*x + W_hh1 . h1 ----------------
        {
            const float xv = x_lds[t*17 + bb];
            #pragma unroll
            for (int j = 0; j < 4; ++j){
                a0[j] = fmaf(wih1r[j],    xv, b1r[j]);
                a1[j] = fmaf(wih1r[4+j],  xv, b1r[4+j]);
                a2[j] = fmaf(wih1r[8+j],  xv, b1r[8+j]);
                a3[j] = fmaf(wih1r[12+j], xv, b1r[12+j]);
            }
            const f16x8 hA = *(const f16x8*)(h1r + rowb + rd0);
            const f16x8 hB = *(const f16x8*)(h1r + rowb + rd1);
            a0 = MFMA(wf1[0][0], hA, a0); a0 = MFMA(wf1[0][1], hB, a0);
            a1 = MFMA(wf1[1][0], hA, a1); a1 = MFMA(wf1[1][1], hB, a1);
            a2 = MFMA(wf1[2][0], hA, a2); a2 = MFMA(wf1[2][1], hB, a2);
            a3 = MFMA(wf1[3][0], hA, a3); a3 = MFMA(wf1[3][1], hB, a3);
            #pragma unroll
            for (int j = 0; j < 4; ++j){
                float i_ = sigf(a0[j]), f_ = sigf(a1[j]);
                float g_ = tanhf_(a2[j]), o_ = sigf(a3[j]);
                c1[j] = fmaf(f_, c1[j], i_*g_);
                hn[j] = (f16)(o_*tanhf_(c1[j]));
            }
            *(f16x4*)(h1w + rowb + wro) = hn;
        }
        __syncthreads();

        // ---------------- Layer 2 ----------------
        {
            #pragma unroll
            for (int j = 0; j < 4; ++j){
                a0[j] = b2r[j]; a1[j] = b2r[4+j]; a2[j] = b2r[8+j]; a3[j] = b2r[12+j];
            }
            const f16x8 iA = *(const f16x8*)(h1w + rowb + rd0);  // h1 new
            const f16x8 iB = *(const f16x8*)(h1w + rowb + rd1);
            const f16x8 hA = *(const f16x8*)(h2r + rowb + rd0);  // h2 old
            const f16x8 hB = *(const f16x8*)(h2r + rowb + rd1);
            a0 = MFMA(w2i[0][0], iA, a0); a0 = MFMA(w2i[0][1], iB, a0);
            a1 = MFMA(w2i[1][0], iA, a1); a1 = MFMA(w2i[1][1], iB, a1);
            a2 = MFMA(w2i[2][0], iA, a2); a2 = MFMA(w2i[2][1], iB, a2);
            a3 = MFMA(w2i[3][0], iA, a3); a3 = MFMA(w2i[3][1], iB, a3);
            a0 = MFMA(w2h[0][0], hA, a0); a0 = MFMA(w2h[0][1], hB, a0);
            a1 = MFMA(w2h[1][0], hA, a1); a1 = MFMA(w2h[1][1], hB, a1);
            a2 = MFMA(w2h[2][0], hA, a2); a2 = MFMA(w2h[2][1], hB, a2);
            a3 = MFMA(w2h[3][0], hA, a3); a3 = MFMA(w2h[3][1], hB, a3);
            #pragma unroll
            for (int j = 0; j < 4; ++j){
                float i_ = sigf(a0[j]), f_ = sigf(a1[j]);
                float g_ = tanhf_(a2[j]), o_ = sigf(a3[j]);
                c2[j] = fmaf(f_, c2[j], i_*g_);
                hn[j] = (f16)(o_*tanhf_(c2[j]));
            }
            *(f16x4*)(h2w + rowb + wro) = hn;
        }
        __syncthreads();

        // ---------------- Layer 3 ----------------
        {
            #pragma unroll
            for (int j = 0; j < 4; ++j){
                a0[j] = b3r[j]; a1[j] = b3r[4+j]; a2[j] = b3r[8+j]; a3[j] = b3r[12+j];
            }
            const f16x8 iA = *(const f16x8*)(h2w + rowb + rd0);  // h2 new
            const f16x8 iB = *(const f16x8*)(h2w + rowb + rd1);
            const f16x8 hA = *(const f16x8*)(h3r + rowb + rd0);  // h3 old
            const f16x8 hB = *(const f16x8*)(h3r + rowb + rd1);
            a0 = MFMA(w3i[0][0], iA, a0); a0 = MFMA(w3i[0][1], iB, a0);
            a1 = MFMA(w3i[1][0], iA, a1); a1 = MFMA(w3i[1][1], iB, a1);
            a2 = MFMA(w3i[2][0], iA, a2); a2 = MFMA(w3i[2][1], iB, a2);
            a3 = MFMA(w3i[3][0], iA, a3); a3 = MFMA(w3i[3][1], iB, a3);
            a0 = MFMA(w3h[0][0], hA, a0); a0 = MFMA(w3h[0][1], hB, a0);
            a1 = MFMA(w3h[1][0], hA, a1); a1 = MFMA(w3h[1][1], hB, a1);
            a2 = MFMA(w3h[2][0], hA, a2); a2 = MFMA(w3h[2][1], hB, a2);
            a3 = MFMA(w3h[3][0], hA, a3); a3 = MFMA(w3h[3][1], hB, a3);
            #pragma unroll
            for (int j = 0; j < 4; ++j){
                float i_ = sigf(a0[j]), f_ = sigf(a1[j]);
                float g_ = tanhf_(a2[j]), o_ = sigf(a3[j]);
                c3[j] = fmaf(f_, c3[j], i_*g_);
                hn[j] = (f16)(o_*tanhf_(c3[j]));
            }
            *(f16x4*)(h3w + rowb + wro) = hn;
        }
        __syncthreads();

        // ---------------- FC head: wave 0 only, both 16-col tiles ----------------
        if (w == 0){
            const f16x8 pA = *(const f16x8*)(h3w + rowb + rd0);  // h3 new
            const f16x8 pB = *(const f16x8*)(h3w + rowb + rd1);
            f32x4 y0, y1;
            #pragma unroll
            for (int j = 0; j < 4; ++j){ y0[j] = fc1br[j]; y1[j] = fc1br[4+j]; }
            y0 = MFMA(wfc[0][0], pA, y0); y0 = MFMA(wfc[0][1], pB, y0);
            y1 = MFMA(wfc[1][0], pA, y1); y1 = MFMA(wfc[1][1], pB, y1);
            float s = 0.f;
            #pragma unroll
            for (int j = 0; j < 4; ++j){
                float u = y0[j]; u = fmaxf(u, 0.2f*u);
                s = fmaf(u, fc2wr[j], s);
                float v = y1[j]; v = fmaxf(v, 0.2f*v);
                s = fmaf(v, fc2wr[4+j], s);
            }
            s += __shfl_xor(s, 16);   // sum over q groups: cols 0..31 complete
            s += __shfl_xor(s, 32);
            if (q == 0) out[(size_t)(b0+bb)*TT + t] = s + fc2bs;
        }
        // no barrier needed: FC reads h3w; next-step L1 touches only h1/x.
    }
}

extern "C" void kernel_launch(void* const* d_in, const int* in_sizes, int n_in,
                              void* d_out, int out_size, void* d_ws, size_t ws_size,
                              hipStream_t stream)
{
    (void)in_sizes; (void)n_in; (void)d_ws; (void)ws_size; (void)out_size;
    const float* x     = (const float*)d_in[0];
    const float* w_ih1 = (const float*)d_in[1];
    const float* w_hh1 = (const float*)d_in[2];
    const float* b1    = (const float*)d_in[3];
    const float* w_ih2 = (const float*)d_in[4];
    const float* w_hh2 = (const float*)d_in[5];
    const float* b2    = (const float*)d_in[6];
    const float* w_ih3 = (const float*)d_in[7];
    const float* w_hh3 = (const float*)d_in[8];
    const float* b3    = (const float*)d_in[9];
    const float* fc1_w = (const float*)d_in[10];
    const float* fc1_b = (const float*)d_in[11];
    const float* fc2_w = (const float*)d_in[12];
    const float* fc2_b = (const float*)d_in[13];

    lstm3_mfma<<<dim3(64), dim3(256), 0, stream>>>(
        x, w_ih1, w_hh1, b1, w_ih2, w_hh2, b2, w_ih3, w_hh3, b3,
        fc1_w, fc1_b, fc2_w, fc2_b, (float*)d_out);
}

// Round 3
// 519.408 us; speedup vs baseline: 4.4072x; 1.6816x over previous
//
#include <hip/hip_runtime.h>

#define TT 512

typedef _Float16 f16;
typedef _Float16 f16x4 __attribute__((ext_vector_type(4)));
typedef _Float16 f16x8 __attribute__((ext_vector_type(8)));
typedef float    f32x4 __attribute__((ext_vector_type(4)));

#define MFMA(A, B, C) __builtin_amdgcn_mfma_f32_16x16x32_f16((A), (B), (C), 0, 0, 0)

#define LOG2E  1.44269504f
#define LOG2E2 2.88539008f

__device__ __forceinline__ float exp2_(float x){
#if __has_builtin(__builtin_amdgcn_exp2f)
    return __builtin_amdgcn_exp2f(x);
#else
    return exp2f(x);
#endif
}
__device__ __forceinline__ float rcp_(float x){
#if __has_builtin(__builtin_amdgcn_rcpf)
    return __builtin_amdgcn_rcpf(x);
#else
    return 1.0f/x;
#endif
}
__device__ __forceinline__ f16x8 ldw8s(const float* p, float s){
    f16x8 r;
    #pragma unroll
    for (int i = 0; i < 8; ++i) r[i] = (f16)(p[i]*s);
    return r;
}

// gates pre-scaled: i/f/o rows by LOG2E, g rows by LOG2E2 (folded into weights+bias)
__device__ __forceinline__ void act4(const f32x4& zi, const f32x4& zf,
                                     const f32x4& zg, const f32x4& zo,
                                     float* c, f16x4& hn){
    #pragma unroll
    for (int j = 0; j < 4; ++j){
        float i_ = rcp_(1.0f + exp2_(-zi[j]));
        float f_ = rcp_(1.0f + exp2_(-zf[j]));
        float g_ = fmaf(-2.0f, rcp_(1.0f + exp2_(zg[j])), 1.0f);   // tanh
        float o_ = rcp_(1.0f + exp2_(-zo[j]));
        c[j] = fmaf(f_, c[j], i_*g_);
        float th = fmaf(-2.0f, rcp_(1.0f + exp2_(LOG2E2*c[j])), 1.0f);
        hn[j] = (f16)(o_*th);
    }
}

// 64 blocks x 768 threads (12 waves), 16 batch elements per block.
// Software pipeline, one barrier per phase:
//   phase p:  waves 0-3 : L1 step t=p       (unit-quarter uq = wid)
//             waves 4-7 : L2 step t=p-1
//             waves 8-11: L3 step t=p-2
//             waves 0,1 : FC  step t=p-3 (one 16-col tile each), out at t=p-4
// Every LDS value read in phase p was written in phase p-1 -> single barrier.
// D layout (16x16x32): col(batch)=lane&15, row=4*(lane>>4)+j.
// Wave's 4 A-tiles = the 4 gates of its 16 units -> i,f,g,o in-lane.
__global__ __launch_bounds__(768, 1) void lstm3_pipe(
    const float* __restrict__ x,
    const float* __restrict__ w_ih1, const float* __restrict__ w_hh1, const float* __restrict__ b1,
    const float* __restrict__ w_ih2, const float* __restrict__ w_hh2, const float* __restrict__ b2,
    const float* __restrict__ w_ih3, const float* __restrict__ w_hh3, const float* __restrict__ b3,
    const float* __restrict__ fc1_w, const float* __restrict__ fc1_b,
    const float* __restrict__ fc2_w, const float* __restrict__ fc2_b,
    float* __restrict__ out)
{
    // h buffers: [layer][parity][16 batch][64 units] f16, XOR-swizzled rows
    __shared__ __align__(16) unsigned char hraw[3*2*2048];
    __shared__ float s_fc[2][2][16];          // [fc tile][t&1][batch]

    const int tid = threadIdx.x;
    const int wid = tid >> 6;
    const int l   = tid & 63;
    const int q   = l >> 4;
    const int bb  = l & 15;
    const int b0  = blockIdx.x * 16;
    const int role = (wid < 4) ? 0 : (wid < 8 ? 1 : 2);
    const int uq   = wid & 3;

    for (int i = tid; i < (int)sizeof(hraw)/4; i += 768)
        ((unsigned int*)hraw)[i] = 0u;
    if (tid < 64) ((float*)s_fc)[tid] = 0.f;

    // ---- persistent weights (f16 A-frags, scales folded) ----
    const float* Wih = (role == 1) ? w_ih2 : w_ih3;
    const float* Whh = (role == 0) ? w_hh1 : (role == 1 ? w_hh2 : w_hh3);
    const float* bp  = (role == 0) ? b1   : (role == 1 ? b2    : b3);

    f16x8 wI[4][2], wH[4][2];
    float bcr[16], wih1r[16];
    #pragma unroll
    for (int g = 0; g < 4; ++g){
        const float sg = (g == 2) ? LOG2E2 : LOG2E;
        const int row = g*64 + uq*16 + bb;
        #pragma unroll
        for (int kh = 0; kh < 2; ++kh){
            wH[g][kh] = ldw8s(Whh + row*64 + kh*32 + q*8, sg);
            if (role != 0) wI[g][kh] = ldw8s(Wih + row*64 + kh*32 + q*8, sg);
        }
        #pragma unroll
        for (int j = 0; j < 4; ++j){
            const int rj = g*64 + uq*16 + 4*q + j;
            bcr[g*4+j] = bp[rj]*sg;
            if (role == 0) wih1r[g*4+j] = w_ih1[rj]*sg;
        }
    }

    // FC fragments (waves 0,1 only; tile ti = wid)
    f16x8 wfc[2];
    float fc1br[4], fc2wr[4];
    const float fc2bs = fc2_b[0];
    if (wid < 2){
        #pragma unroll
        for (int kh = 0; kh < 2; ++kh)
            wfc[kh] = ldw8s(fc1_w + (wid*16 + bb)*64 + kh*32 + q*8, 1.0f);
        #pragma unroll
        for (int j = 0; j < 4; ++j){
            fc1br[j] = fc1_b[wid*16 + 4*q + j];
            fc2wr[j] = fc2_w[wid*16 + 4*q + j];
        }
    }

    float c[4] = {0.f, 0.f, 0.f, 0.f};

    // t-invariant LDS byte offsets (R1-verified swizzle)
    const int rowb = bb*128;
    const int swz  = 16*(bb&7);
    const int rdA  = rowb + ((16*q     ) ^ swz);
    const int rdB  = rowb + ((16*q + 64) ^ swz);
    const int wro  = rowb + ((uq*32 + 8*q) ^ swz);

    float xv = (role == 0) ? x[(size_t)(b0+bb)*TT] : 0.f;   // t=0 prefetch

    __syncthreads();

    #pragma unroll 1
    for (int p = 0; p < TT + 4; ++p){
        if (role == 0){
            const int t = p;
            if (t < TT){
                const unsigned char* hr = hraw + (((t-1)&1) << 11);
                unsigned char*       hw = hraw + (((t  )&1) << 11);
                const f16x8 hA = *(const f16x8*)(hr + rdA);
                const f16x8 hB = *(const f16x8*)(hr + rdB);
                f32x4 a0, a1, a2, a3;
                #pragma unroll
                for (int j = 0; j < 4; ++j){
                    a0[j] = fmaf(wih1r[j],    xv, bcr[j]);
                    a1[j] = fmaf(wih1r[4+j],  xv, bcr[4+j]);
                    a2[j] = fmaf(wih1r[8+j],  xv, bcr[8+j]);
                    a3[j] = fmaf(wih1r[12+j], xv, bcr[12+j]);
                }
                a0 = MFMA(wH[0][0], hA, a0); a0 = MFMA(wH[0][1], hB, a0);
                a1 = MFMA(wH[1][0], hA, a1); a1 = MFMA(wH[1][1], hB, a1);
                a2 = MFMA(wH[2][0], hA, a2); a2 = MFMA(wH[2][1], hB, a2);
                a3 = MFMA(wH[3][0], hA, a3); a3 = MFMA(wH[3][1], hB, a3);
                f16x4 hn;
                act4(a0, a1, a2, a3, c, hn);
                *(f16x4*)(hw + wro) = hn;
                if (t+1 < TT) xv = x[(size_t)(b0+bb)*TT + (t+1)];
            }
            if (wid < 2){
                const int tf = p - 3;
                if (tf >= 0 && tf < TT){
                    const unsigned char* h3r = hraw + 4*2048 + ((tf&1) << 11);
                    const f16x8 pA = *(const f16x8*)(h3r + rdA);
                    const f16x8 pB = *(const f16x8*)(h3r + rdB);
                    f32x4 y;
                    #pragma unroll
                    for (int j = 0; j < 4; ++j) y[j] = fc1br[j];
                    y = MFMA(wfc[0], pA, y);
                    y = MFMA(wfc[1], pB, y);
                    float s = 0.f;
                    #pragma unroll
                    for (int j = 0; j < 4; ++j){
                        float u = fmaxf(y[j], 0.2f*y[j]);     // leaky_relu(0.2)
                        s = fmaf(u, fc2wr[j], s);
                    }
                    s += __shfl_xor(s, 16);
                    s += __shfl_xor(s, 32);
                    if (l < 16) s_fc[wid][tf&1][l] = s;
                }
                const int to = p - 4;
                if (wid == 1 && to >= 0 && to < TT && l < 16)
                    out[(size_t)(b0+l)*TT + to] =
                        s_fc[0][to&1][l] + s_fc[1][to&1][l] + fc2bs;
            }
        } else {
            const int t = (role == 1) ? (p - 1) : (p - 2);
            if (t >= 0 && t < TT){
                const int inL  = (role == 1) ? 0 : 1;       // h1 / h2 input layer
                const int myL  = (role == 1) ? 1 : 2;       // h2 / h3 state layer
                const unsigned char* ir = hraw + inL*4096 + (((t  )&1) << 11);
                const unsigned char* hr = hraw + myL*4096 + (((t-1)&1) << 11);
                unsigned char*       hw = hraw + myL*4096 + (((t  )&1) << 11);
                const f16x8 iA = *(const f16x8*)(ir + rdA);
                const f16x8 iB = *(const f16x8*)(ir + rdB);
                const f16x8 hA = *(const f16x8*)(hr + rdA);
                const f16x8 hB = *(const f16x8*)(hr + rdB);
                f32x4 a0, a1, a2, a3;
                #pragma unroll
                for (int j = 0; j < 4; ++j){
                    a0[j] = bcr[j]; a1[j] = bcr[4+j]; a2[j] = bcr[8+j]; a3[j] = bcr[12+j];
                }
                a0 = MFMA(wI[0][0], iA, a0); a1 = MFMA(wI[1][0], iA, a1);
                a2 = MFMA(wI[2][0], iA, a2); a3 = MFMA(wI[3][0], iA, a3);
                a0 = MFMA(wI[0][1], iB, a0); a1 = MFMA(wI[1][1], iB, a1);
                a2 = MFMA(wI[2][1], iB, a2); a3 = MFMA(wI[3][1], iB, a3);
                a0 = MFMA(wH[0][0], hA, a0); a1 = MFMA(wH[1][0], hA, a1);
                a2 = MFMA(wH[2][0], hA, a2); a3 = MFMA(wH[3][0], hA, a3);
                a0 = MFMA(wH[0][1], hB, a0); a1 = MFMA(wH[1][1], hB, a1);
                a2 = MFMA(wH[2][1], hB, a2); a3 = MFMA(wH[3][1], hB, a3);
                f16x4 hn;
                act4(a0, a1, a2, a3, c, hn);
                *(f16x4*)(hw + wro) = hn;
            }
        }
        __syncthreads();
    }
}

extern "C" void kernel_launch(void* const* d_in, const int* in_sizes, int n_in,
                              void* d_out, int out_size, void* d_ws, size_t ws_size,
                              hipStream_t stream)
{
    (void)in_sizes; (void)n_in; (void)d_ws; (void)ws_size; (void)out_size;
    const float* x     = (const float*)d_in[0];
    const float* w_ih1 = (const float*)d_in[1];
    const float* w_hh1 = (const float*)d_in[2];
    const float* b1    = (const float*)d_in[3];
    const float* w_ih2 = (const float*)d_in[4];
    const float* w_hh2 = (const float*)d_in[5];
    const float* b2    = (const float*)d_in[6];
    const float* w_ih3 = (const float*)d_in[7];
    const float* w_hh3 = (const float*)d_in[8];
    const float* b3    = (const float*)d_in[9];
    const float* fc1_w = (const float*)d_in[10];
    const float* fc1_b = (const float*)d_in[11];
    const float* fc2_w = (const float*)d_in[12];
    const float* fc2_b = (const float*)d_in[13];

    lstm3_pipe<<<dim3(64), dim3(768), 0, stream>>>(
        x, w_ih1, w_hh1, b1, w_ih2, w_hh2, b2, w_ih3, w_hh3, b3,
        fc1_w, fc1_b, fc2_w, fc2_b, (float*)d_out);
}